// Round 10
// baseline (178.227 us; speedup 1.0000x reference)
//
#include <hip/hip_runtime.h>
#include <hip/hip_bf16.h>

#define BB 2
#define LL 4096
#define DD 128
#define HH 4

typedef unsigned short u16;
typedef unsigned int u32;
typedef __attribute__((ext_vector_type(8))) short short8;   // 8 bf16
typedef __attribute__((ext_vector_type(4))) float floatx4;

union PFrag { short8 s; u32 u[4]; };

__device__ __forceinline__ u16 f2bf(float f) {
    union { float f; u32 u; } v; v.f = f;
    return (u16)((v.u + 0x7fffu + ((v.u >> 16) & 1u)) >> 16);
}

__device__ __forceinline__ float bf2f(u16 u) {
    union { u32 u; float f; } v; v.u = (u32)u << 16;
    return v.f;
}

// packed f32x2 -> bf16x2 (low = a)
__device__ __forceinline__ u32 pk2bf(float a, float b) {
    union { __hip_bfloat162 h; u32 u; } v;
    v.h = __float22bfloat162_rn(float2{a, b});
    return v.u;
}

// async global->LDS, 16B per lane; lds dest must be wave-uniform base
__device__ __forceinline__ void gld16(const u16* g, u16* l) {
    __builtin_amdgcn_global_load_lds((const __attribute__((address_space(1))) void*)g,
                                     (__attribute__((address_space(3))) void*)l, 16, 0, 0);
}

// # of interior (non-diagonal) 512-key chunks for q-tiles t' < t
__device__ __forceinline__ int pfx2(int t) {
    int a = t >> 2, b = t & 3;
    return 2 * a * (a - 1) + a * b;
}

// z=0: x, z=1..4: weights, z=5: zero l_acc
__global__ __launch_bounds__(256) void cvt_all(const float* __restrict__ x,
                                               const float* __restrict__ wq,
                                               const float* __restrict__ wk,
                                               const float* __restrict__ wv,
                                               const float* __restrict__ wo,
                                               u16* xb, u16* wqb, u16* wkb,
                                               u16* wvb, u16* wob,
                                               float* l_acc) {
    int z = blockIdx.y;
    if (z == 5) {
        int i = (blockIdx.x * 256 + threadIdx.x) * 4;
        if (i < 8 * LL) *(float4*)(l_acc + i) = (float4){0.f, 0.f, 0.f, 0.f};
        return;
    }
    const float* src; u16* dst; int n;
    if      (z == 0) { src = x;  dst = xb;  n = BB * LL * DD; }
    else if (z == 1) { src = wq; dst = wqb; n = HH * DD * DD; }
    else if (z == 2) { src = wk; dst = wkb; n = HH * DD * DD; }
    else if (z == 3) { src = wv; dst = wvb; n = HH * DD * DD; }
    else             { src = wo; dst = wob; n = DD * HH * DD; }
    int i = (blockIdx.x * 256 + threadIdx.x) * 4;
    if (i >= n) return;
    float4 v = *(const float4*)(src + i);
    ushort4 o;
    o.x = f2bf(v.x); o.y = f2bf(v.y); o.z = f2bf(v.z); o.w = f2bf(v.w);
    *(ushort4*)(dst + i) = o;
}

// Tiled QKV projection: 128x128 output tile per block, K=128 one-shot.
__global__ __launch_bounds__(256) void proj_qkv(const u16* __restrict__ xb,
                                                const u16* __restrict__ wqb,
                                                const u16* __restrict__ wkb,
                                                const u16* __restrict__ wvb,
                                                u16* __restrict__ Qb,
                                                u16* __restrict__ Kb,
                                                u16* __restrict__ Vt) {
    __shared__ __align__(16) u16 At[128 * 128];
    __shared__ __align__(16) u16 Wt[128 * 128];
    int lane = threadIdx.x & 63;
    int w    = threadIdx.x >> 6;
    int c = lane & 15, g = lane >> 4;
    int mt = blockIdx.x;                  // 0..63
    int nt = blockIdx.y;                  // 0..11
    int z = nt >> 2, h = nt & 3;
    const u16* Wg = ((z == 0) ? wqb : (z == 1) ? wkb : wvb) + h * 128 * DD;
    const u16* Ag = xb + (size_t)mt * 128 * DD;

#pragma unroll
    for (int i = 0; i < 8; i++) {
        int row = i * 16 + w * 4 + (lane >> 4);
        int cc  = (lane & 15) ^ (row & 15);
        gld16(Ag + row * DD + cc * 8, &At[(i * 16 + w * 4) * 128]);
    }
#pragma unroll
    for (int i = 0; i < 8; i++) {
        int row = i * 16 + w * 4 + (lane >> 4);
        int cc  = (lane & 15) ^ (row & 15);
        gld16(Wg + row * DD + cc * 8, &Wt[(i * 16 + w * 4) * 128]);
    }
    __syncthreads();

    const u16* Abuf = (z < 2) ? At : Wt;   // a-operand rows (m)
    const u16* Bbuf = (z < 2) ? Wt : At;   // b-operand rows (n)

    floatx4 acc[2][8];
#pragma unroll
    for (int m2 = 0; m2 < 2; m2++)
#pragma unroll
        for (int n2 = 0; n2 < 8; n2++) acc[m2][n2] = (floatx4){0.f, 0.f, 0.f, 0.f};

#pragma unroll
    for (int kk = 0; kk < 4; kk++) {
        short8 a0, a1, bf[8];
        {
            int r0 = w * 32 + c;
            int r1 = r0 + 16;
            a0 = *(const short8*)(&Abuf[r0 * 128 + (((g + 4 * kk) ^ (r0 & 15)) * 8)]);
            a1 = *(const short8*)(&Abuf[r1 * 128 + (((g + 4 * kk) ^ (r1 & 15)) * 8)]);
        }
#pragma unroll
        for (int n2 = 0; n2 < 8; n2++) {
            int rn = n2 * 16 + c;
            bf[n2] = *(const short8*)(&Bbuf[rn * 128 + (((g + 4 * kk) ^ (rn & 15)) * 8)]);
        }
#pragma unroll
        for (int n2 = 0; n2 < 8; n2++) {
            acc[0][n2] = __builtin_amdgcn_mfma_f32_16x16x32_bf16(a0, bf[n2], acc[0][n2], 0, 0, 0);
            acc[1][n2] = __builtin_amdgcn_mfma_f32_16x16x32_bf16(a1, bf[n2], acc[1][n2], 0, 0, 0);
        }
    }

    if (z < 2) {
        u16* out = (z == 0) ? Qb : Kb;
#pragma unroll
        for (int m2 = 0; m2 < 2; m2++)
#pragma unroll
            for (int r = 0; r < 4; r++) {
                int lg = mt * 128 + w * 32 + m2 * 16 + g * 4 + r;
                int b_ = lg >> 12, l = lg & 4095;
                u16* op = out + ((size_t)(b_ * HH + h) * LL + l) * DD + c;
#pragma unroll
                for (int n2 = 0; n2 < 8; n2++) op[n2 * 16] = f2bf(acc[m2][n2][r]);
            }
    } else {
        int b_ = mt >> 5;
        int lbase = (mt & 31) * 128;
#pragma unroll
        for (int m2 = 0; m2 < 2; m2++)
#pragma unroll
            for (int r = 0; r < 4; r++) {
                int e = w * 32 + m2 * 16 + g * 4 + r;
                u16* op = Vt + ((size_t)(b_ * HH + h) * DD + e) * LL + lbase + c;
#pragma unroll
                for (int n2 = 0; n2 < 8; n2++) op[n2 * 16] = f2bf(acc[m2][n2][r]);
            }
    }
}

// Flash attention, causal, no-max softmax. Block = 4 waves x 32 q-rows = 128
// q-rows of one head over one 512-key chunk (<=16 steps). K staged in LDS
// (dbuf 16KB, XOR-swizzled, phase-conflict-free); V read DIRECT from global
// (16B contiguous B-fragments; 4 barrier-converged waves share addrs -> L1
// dedup; no 64B-row LDS bank conflicts). Partials: diag chunk -> base tile,
// interior chunks -> private bf16 slots; combined in norm_cast.
__global__ __launch_bounds__(256) void flash_attn(const u16* __restrict__ Q,
                                                  const u16* __restrict__ K,
                                                  const u16* __restrict__ Vt,
                                                  u16* __restrict__ basep,
                                                  u16* __restrict__ slots,
                                                  float* __restrict__ l_acc) {
    __shared__ __align__(16) u16 Kls[2][32 * 128];   // 16KB: rows k (256B), swizzled

    int lane = threadIdx.x & 63;
    int w    = threadIdx.x >> 6;          // 0..3
    int c = lane & 15, g = lane >> 4;

    int bid  = blockIdx.x;                // 0..1151
    int head = bid & 7;                   // b*H + h
    int i    = bid >> 3;                  // 0..143
    int t, ch;
    if (i < 120) {                        // full 16-step chunks, longest-lived first
        int rem = i; ch = 0;
        while (rem >= 29 - 4 * ch) { rem -= 29 - 4 * ch; ch++; }
        t = 31 - rem;
    } else {
        int j = i - 120;                  // partial diag chunks, size desc
        if (j < 8)       { t = 30 - 4 * j;        ch = (t - 2) >> 2; }
        else if (j < 16) { t = 29 - 4 * (j - 8);  ch = (t - 1) >> 2; }
        else             { t = 28 - 4 * (j - 16); ch = t >> 2; }
    }

    int kstart = ch << 9;
    int kend   = min((t + 1) << 7, kstart + 512);
    int nsteps = (kend - kstart) >> 5;    // 4..16, block-uniform

    int qb = t * 128 + w * 32;
    int my_steps = min(nsteps, ((qb + 31 - kstart) >> 5) + 1);

    // Q B-fragments for two q-halves (n=c=q-row, k=g*8..)
    short8 bq0[4], bq1[4];
    {
        const u16* qp0 = Q + ((size_t)head * LL + qb + c) * DD + g * 8;
        const u16* qp1 = qp0 + 16 * DD;
#pragma unroll
        for (int kk = 0; kk < 4; kk++) {
            bq0[kk] = *(const short8*)(qp0 + kk * 32);
            bq1[kk] = *(const short8*)(qp1 + kk * 32);
        }
    }

    floatx4 o0[8], o1[8];
#pragma unroll
    for (int tt = 0; tt < 8; tt++) {
        o0[tt] = (floatx4){0.f, 0.f, 0.f, 0.f};
        o1[tt] = (floatx4){0.f, 0.f, 0.f, 0.f};
    }
    float lsum0 = 0.f, lsum1 = 0.f;

    int s0 = c + (((g << 1) & 3) << 4);
    int s1 = c + ((((g << 1) | 1) & 3) << 4);
    bool hi = (g >= 2);

    const u16* Kg0 = K  + ((size_t)head * LL + kstart) * DD;
    const u16* vp0 = Vt + ((size_t)head * DD + c) * LL + kstart + g * 8;

    int q0 = w * 64 + lane;
    int r0 = q0 >> 4, cc0 = (q0 & 15) ^ (r0 & 15);
    int r1 = r0 + 16,  cc1 = (q0 & 15) ^ (r1 & 15);

#define STAGE(s) {                                                          \
        int buf_ = (s) & 1; int kb_ = (s) << 5;                             \
        const u16* Kg = Kg0 + (size_t)kb_ * DD;                             \
        gld16(Kg + r0 * DD + cc0 * 8, &Kls[buf_][w * 512]);                 \
        gld16(Kg + r1 * DD + cc1 * 8, &Kls[buf_][2048 + w * 512]);          \
    }

    STAGE(0);

    for (int j = 0; j < nsteps; ++j) {
        __syncthreads();
        if (j + 1 < nsteps) STAGE(j + 1);
        if (j < my_steps) {
            int kb = kstart + (j << 5);
            const u16* Kb_ = &Kls[j & 1][0];

            // V fragments direct from global (consumed after softmax)
            short8 vb[8];
#pragma unroll
            for (int tt = 0; tt < 8; tt++)
                vb[tt] = *(const short8*)(vp0 + (size_t)tt * 16 * LL + (j << 5));

            floatx4 st00 = {0,0,0,0}, st01 = {0,0,0,0};
            floatx4 st10 = {0,0,0,0}, st11 = {0,0,0,0};
            {
                short8 ka[4];
#pragma unroll
                for (int kk = 0; kk < 4; kk++)
                    ka[kk] = *(const short8*)(Kb_ + c * 128 + (((g + 4 * kk) ^ c)) * 8);
#pragma unroll
                for (int kk = 0; kk < 4; kk++) {
                    st00 = __builtin_amdgcn_mfma_f32_16x16x32_bf16(ka[kk], bq0[kk], st00, 0, 0, 0);
                    st10 = __builtin_amdgcn_mfma_f32_16x16x32_bf16(ka[kk], bq1[kk], st10, 0, 0, 0);
                }
#pragma unroll
                for (int kk = 0; kk < 4; kk++)
                    ka[kk] = *(const short8*)(Kb_ + (16 + c) * 128 + (((g + 4 * kk) ^ c)) * 8);
#pragma unroll
                for (int kk = 0; kk < 4; kk++) {
                    st01 = __builtin_amdgcn_mfma_f32_16x16x32_bf16(ka[kk], bq0[kk], st01, 0, 0, 0);
                    st11 = __builtin_amdgcn_mfma_f32_16x16x32_bf16(ka[kk], bq1[kk], st11, 0, 0, 0);
                }
            }

            PFrag au0, au1;
#pragma unroll
            for (int qh = 0; qh < 2; qh++) {
                floatx4 sa = qh ? st10 : st00;
                floatx4 sb = qh ? st11 : st01;
                int qbh = qb + qh * 16;
                float p[8];
                if (kb + 31 > qbh) {
                    int q_c = qbh + c;
#pragma unroll
                    for (int r = 0; r < 4; r++) {
                        int k0 = kb + g * 4 + r;
                        p[r]     = (k0      <= q_c) ? sa[r] : -INFINITY;
                        p[4 + r] = (k0 + 16 <= q_c) ? sb[r] : -INFINITY;
                    }
                } else {
#pragma unroll
                    for (int r = 0; r < 4; r++) { p[r] = sa[r]; p[4 + r] = sb[r]; }
                }
                float ls = 0.f;
#pragma unroll
                for (int i2 = 0; i2 < 8; i2++) { p[i2] = __expf(p[i2]); ls += p[i2]; }
                if (qh) lsum1 += ls; else lsum0 += ls;

                u32 pk00 = pk2bf(p[0], p[1]);
                u32 pk01 = pk2bf(p[2], p[3]);
                u32 pk10 = pk2bf(p[4], p[5]);
                u32 pk11 = pk2bf(p[6], p[7]);
                u32 x00 = (u32)__shfl((int)pk00, s0), x10 = (u32)__shfl((int)pk10, s0);
                u32 x01 = (u32)__shfl((int)pk01, s0), x11 = (u32)__shfl((int)pk11, s0);
                u32 y00 = (u32)__shfl((int)pk00, s1), y10 = (u32)__shfl((int)pk10, s1);
                u32 y01 = (u32)__shfl((int)pk01, s1), y11 = (u32)__shfl((int)pk11, s1);
                PFrag* au = qh ? &au1 : &au0;
                au->u[0] = hi ? x10 : x00;
                au->u[1] = hi ? x11 : x01;
                au->u[2] = hi ? y10 : y00;
                au->u[3] = hi ? y11 : y01;
            }

#pragma unroll
            for (int tt = 0; tt < 8; tt++) {
                o0[tt] = __builtin_amdgcn_mfma_f32_16x16x32_bf16(au0.s, vb[tt], o0[tt], 0, 0, 0);
                o1[tt] = __builtin_amdgcn_mfma_f32_16x16x32_bf16(au1.s, vb[tt], o1[tt], 0, 0, 0);
            }
        }
    }
#undef STAGE

    lsum0 += __shfl_xor(lsum0, 16); lsum0 += __shfl_xor(lsum0, 32);
    lsum1 += __shfl_xor(lsum1, 16); lsum1 += __shfl_xor(lsum1, 32);
    if (g == 0) {
        atomicAdd(&l_acc[head * LL + qb + c],      lsum0);
        atomicAdd(&l_acc[head * LL + qb + 16 + c], lsum1);
    }

    // partial O store as bf16 (one owner per element)
    bool diag = (kstart + 512 >= ((t + 1) << 7));
    u16* dst0 = diag ? basep + ((size_t)head * LL + t * 128) * 128
                     : slots + ((size_t)(head * 112 + pfx2(t) + ch)) * 16384;
    dst0 += (size_t)(w * 32) * 128;
#pragma unroll
    for (int r = 0; r < 4; r++) {
        u16* d0 = dst0 + (g * 4 + r) * 128 + c;
        u16* d1 = d0 + 16 * 128;
#pragma unroll
        for (int tt = 0; tt < 8; tt++) {
            d0[tt * 16] = f2bf(o0[tt][r]);
            d1[tt * 16] = f2bf(o1[tt][r]);
        }
    }
}

// ctx_bf16 = f2bf((base + sum slots) / l)
__global__ __launch_bounds__(256) void norm_cast(const u16* __restrict__ basep,
                                                 const u16* __restrict__ slots,
                                                 const float* __restrict__ l_acc,
                                                 u16* __restrict__ ctx) {
    int i = blockIdx.x * 256 + threadIdx.x;
    int e4 = i * 4;
    int col = e4 & 511;
    int bl  = e4 >> 9;
    int b_ = bl >> 12, l = bl & 4095;
    int h = col >> 7, d = col & 127;
    int head = b_ * HH + h;
    int t = l >> 7;
    int nx = t >> 2;                       // # interior chunks feeding this tile

    ushort4 bv = *(const ushort4*)(basep + ((size_t)head * LL + l) * 128 + d);
    float v0 = bf2f(bv.x), v1 = bf2f(bv.y), v2 = bf2f(bv.z), v3 = bf2f(bv.w);
    if (nx > 0) {
        int sb = head * 112 + pfx2(t);
        for (int x = 0; x < nx; x++) {
            ushort4 sv = *(const ushort4*)(slots + (size_t)(sb + x) * 16384 + (l & 127) * 128 + d);
            v0 += bf2f(sv.x); v1 += bf2f(sv.y); v2 += bf2f(sv.z); v3 += bf2f(sv.w);
        }
    }
    float inv = 1.f / l_acc[head * LL + l];
    ushort4 o;
    o.x = f2bf(v0 * inv); o.y = f2bf(v1 * inv);
    o.z = f2bf(v2 * inv); o.w = f2bf(v3 * inv);
    *(ushort4*)(ctx + e4) = o;
}

// y = ctx(8192x512) @ Wo(128x512)^T -> fp32 [B,L,128]
__global__ __launch_bounds__(256) void proj_out(const u16* __restrict__ ctx,
                                                const u16* __restrict__ wo,
                                                float* __restrict__ y) {
    __shared__ __align__(16) u16 At[2][128 * 64];
    __shared__ __align__(16) u16 Wt[2][128 * 64];
    int lane = threadIdx.x & 63;
    int w    = threadIdx.x >> 6;
    int c = lane & 15, g = lane >> 4;
    int mt = blockIdx.x;                  // 0..63
    const u16* Ag = ctx + (size_t)mt * 128 * 512;

#define PSTAGE(kc) {                                                        \
        int buf_ = (kc) & 1; int ks_ = (kc) * 64;                           \
        _Pragma("unroll")                                                   \
        for (int i = 0; i < 4; i++) {                                       \
            int row = i * 32 + w * 8 + (lane >> 3);                         \
            int cc  = (lane & 7) ^ (row & 7);                               \
            gld16(Ag + (size_t)row * 512 + ks_ + cc * 8,                    \
                  &At[buf_][(i * 32 + w * 8) * 64]);                        \
            gld16(wo + (size_t)row * 512 + ks_ + cc * 8,                    \
                  &Wt[buf_][(i * 32 + w * 8) * 64]);                        \
        }                                                                   \
    }

    floatx4 acc[2][8];
#pragma unroll
    for (int m2 = 0; m2 < 2; m2++)
#pragma unroll
        for (int n2 = 0; n2 < 8; n2++) acc[m2][n2] = (floatx4){0.f, 0.f, 0.f, 0.f};

    PSTAGE(0);
    for (int kc = 0; kc < 8; kc++) {
        __syncthreads();
        if (kc + 1 < 8) PSTAGE(kc + 1);
        int buf = kc & 1;
#pragma unroll
        for (int kk = 0; kk < 2; kk++) {
            int G = g + 4 * kk;
            short8 a0, a1, bf[8];
            {
                int ra = w * 32 + c;
                int rb = ra + 16;
                a0 = *(const short8*)(&At[buf][ra * 64 + ((G ^ (ra & 7)) * 8)]);
                a1 = *(const short8*)(&At[buf][rb * 64 + ((G ^ (rb & 7)) * 8)]);
            }
#pragma unroll
            for (int n2 = 0; n2 < 8; n2++) {
                int rn = n2 * 16 + c;
                bf[n2] = *(const short8*)(&Wt[buf][rn * 64 + ((G ^ (rn & 7)) * 8)]);
            }
#pragma unroll
            for (int n2 = 0; n2 < 8; n2++) {
                acc[0][n2] = __builtin_amdgcn_mfma_f32_16x16x32_bf16(a0, bf[n2], acc[0][n2], 0, 0, 0);
                acc[1][n2] = __builtin_amdgcn_mfma_f32_16x16x32_bf16(a1, bf[n2], acc[1][n2], 0, 0, 0);
            }
        }
    }
#undef PSTAGE

#pragma unroll
    for (int m2 = 0; m2 < 2; m2++)
#pragma unroll
        for (int r = 0; r < 4; r++) {
            int m = mt * 128 + w * 32 + m2 * 16 + g * 4 + r;
            float* yp = y + (size_t)m * 128 + c;
#pragma unroll
            for (int n2 = 0; n2 < 8; n2++) yp[n2 * 16] = acc[m2][n2][r];
        }
}

extern "C" void kernel_launch(void* const* d_in, const int* in_sizes, int n_in,
                              void* d_out, int out_size, void* d_ws, size_t ws_size,
                              hipStream_t stream) {
    const float* x  = (const float*)d_in[0];
    const float* Wq = (const float*)d_in[1];
    const float* Wk = (const float*)d_in[2];
    const float* Wv = (const float*)d_in[3];
    const float* Wo = (const float*)d_in[4];
    float* y = (float*)d_out;

    u16* ws  = (u16*)d_ws;
    u16* xb  = ws;
    u16* wqb = xb  + BB * LL * DD;
    u16* wkb = wqb + HH * DD * DD;
    u16* wvb = wkb + HH * DD * DD;
    u16* wob = wvb + HH * DD * DD;
    u16* Qb  = wob + DD * HH * DD;          // [B,H,L,128]
    u16* Kb  = Qb  + BB * HH * LL * DD;
    u16* Vt  = Kb  + BB * HH * LL * DD;     // [B,H,128,L]
    u16* ctx = Vt  + BB * HH * LL * DD;     // [B,L,512] bf16
    u16* basep = ctx + (size_t)BB * LL * HH * DD;        // [8][L][128] bf16
    u16* slots = basep + (size_t)8 * LL * 128;           // 896 x 16384 bf16
    float* l_acc = (float*)(slots + (size_t)896 * 16384);// [8][L]

    cvt_all<<<dim3(1024, 6), 256, 0, stream>>>(x, Wq, Wk, Wv, Wo,
                                               xb, wqb, wkb, wvb, wob, l_acc);
    proj_qkv<<<dim3(64, 12), 256, 0, stream>>>(xb, wqb, wkb, wvb, Qb, Kb, Vt);
    flash_attn<<<dim3(1152), 256, 0, stream>>>(Qb, Kb, Vt, basep, slots, l_acc);
    norm_cast<<<dim3(4096), 256, 0, stream>>>(basep, slots, l_acc, ctx);
    proj_out<<<dim3(64), 256, 0, stream>>>(ctx, wob, y);
}

// Round 11
// 174.803 us; speedup vs baseline: 1.0196x; 1.0196x over previous
//
#include <hip/hip_runtime.h>
#include <hip/hip_bf16.h>

#define BB 2
#define LL 4096
#define DD 128
#define HH 4

typedef unsigned short u16;
typedef unsigned int u32;
typedef __attribute__((ext_vector_type(8))) short short8;   // 8 bf16
typedef __attribute__((ext_vector_type(4))) float floatx4;

union PFrag { short8 s; u32 u[4]; };

__device__ __forceinline__ u16 f2bf(float f) {
    union { float f; u32 u; } v; v.f = f;
    return (u16)((v.u + 0x7fffu + ((v.u >> 16) & 1u)) >> 16);
}

__device__ __forceinline__ float bf2f(u16 u) {
    union { u32 u; float f; } v; v.u = (u32)u << 16;
    return v.f;
}

// packed f32x2 -> bf16x2 (low = a)
__device__ __forceinline__ u32 pk2bf(float a, float b) {
    union { __hip_bfloat162 h; u32 u; } v;
    v.h = __float22bfloat162_rn(float2{a, b});
    return v.u;
}

// async global->LDS, 16B per lane; lds dest must be wave-uniform base
__device__ __forceinline__ void gld16(const u16* g, u16* l) {
    __builtin_amdgcn_global_load_lds((const __attribute__((address_space(1))) void*)g,
                                     (__attribute__((address_space(3))) void*)l, 16, 0, 0);
}

// # of interior (non-diagonal) 512-key chunks for q-tiles t' < t
__device__ __forceinline__ int pfx2(int t) {
    int a = t >> 2, b = t & 3;
    return 2 * a * (a - 1) + a * b;
}

// z=0: x, z=1..4: weights, z=5: zero l_acc
__global__ __launch_bounds__(256) void cvt_all(const float* __restrict__ x,
                                               const float* __restrict__ wq,
                                               const float* __restrict__ wk,
                                               const float* __restrict__ wv,
                                               const float* __restrict__ wo,
                                               u16* xb, u16* wqb, u16* wkb,
                                               u16* wvb, u16* wob,
                                               float* l_acc) {
    int z = blockIdx.y;
    if (z == 5) {
        int i = (blockIdx.x * 256 + threadIdx.x) * 4;
        if (i < 8 * LL) *(float4*)(l_acc + i) = (float4){0.f, 0.f, 0.f, 0.f};
        return;
    }
    const float* src; u16* dst; int n;
    if      (z == 0) { src = x;  dst = xb;  n = BB * LL * DD; }
    else if (z == 1) { src = wq; dst = wqb; n = HH * DD * DD; }
    else if (z == 2) { src = wk; dst = wkb; n = HH * DD * DD; }
    else if (z == 3) { src = wv; dst = wvb; n = HH * DD * DD; }
    else             { src = wo; dst = wob; n = DD * HH * DD; }
    int i = (blockIdx.x * 256 + threadIdx.x) * 4;
    if (i >= n) return;
    float4 v = *(const float4*)(src + i);
    ushort4 o;
    o.x = f2bf(v.x); o.y = f2bf(v.y); o.z = f2bf(v.z); o.w = f2bf(v.w);
    *(ushort4*)(dst + i) = o;
}

// Tiled QKV projection: 128x128 output tile per block, K=128 one-shot.
__global__ __launch_bounds__(256) void proj_qkv(const u16* __restrict__ xb,
                                                const u16* __restrict__ wqb,
                                                const u16* __restrict__ wkb,
                                                const u16* __restrict__ wvb,
                                                u16* __restrict__ Qb,
                                                u16* __restrict__ Kb,
                                                u16* __restrict__ Vt) {
    __shared__ __align__(16) u16 At[128 * 128];
    __shared__ __align__(16) u16 Wt[128 * 128];
    int lane = threadIdx.x & 63;
    int w    = threadIdx.x >> 6;
    int c = lane & 15, g = lane >> 4;
    int mt = blockIdx.x;                  // 0..63
    int nt = blockIdx.y;                  // 0..11
    int z = nt >> 2, h = nt & 3;
    const u16* Wg = ((z == 0) ? wqb : (z == 1) ? wkb : wvb) + h * 128 * DD;
    const u16* Ag = xb + (size_t)mt * 128 * DD;

#pragma unroll
    for (int i = 0; i < 8; i++) {
        int row = i * 16 + w * 4 + (lane >> 4);
        int cc  = (lane & 15) ^ (row & 15);
        gld16(Ag + row * DD + cc * 8, &At[(i * 16 + w * 4) * 128]);
    }
#pragma unroll
    for (int i = 0; i < 8; i++) {
        int row = i * 16 + w * 4 + (lane >> 4);
        int cc  = (lane & 15) ^ (row & 15);
        gld16(Wg + row * DD + cc * 8, &Wt[(i * 16 + w * 4) * 128]);
    }
    __syncthreads();

    const u16* Abuf = (z < 2) ? At : Wt;   // a-operand rows (m)
    const u16* Bbuf = (z < 2) ? Wt : At;   // b-operand rows (n)

    floatx4 acc[2][8];
#pragma unroll
    for (int m2 = 0; m2 < 2; m2++)
#pragma unroll
        for (int n2 = 0; n2 < 8; n2++) acc[m2][n2] = (floatx4){0.f, 0.f, 0.f, 0.f};

#pragma unroll
    for (int kk = 0; kk < 4; kk++) {
        short8 a0, a1, bf[8];
        {
            int r0 = w * 32 + c;
            int r1 = r0 + 16;
            a0 = *(const short8*)(&Abuf[r0 * 128 + (((g + 4 * kk) ^ (r0 & 15)) * 8)]);
            a1 = *(const short8*)(&Abuf[r1 * 128 + (((g + 4 * kk) ^ (r1 & 15)) * 8)]);
        }
#pragma unroll
        for (int n2 = 0; n2 < 8; n2++) {
            int rn = n2 * 16 + c;
            bf[n2] = *(const short8*)(&Bbuf[rn * 128 + (((g + 4 * kk) ^ (rn & 15)) * 8)]);
        }
#pragma unroll
        for (int n2 = 0; n2 < 8; n2++) {
            acc[0][n2] = __builtin_amdgcn_mfma_f32_16x16x32_bf16(a0, bf[n2], acc[0][n2], 0, 0, 0);
            acc[1][n2] = __builtin_amdgcn_mfma_f32_16x16x32_bf16(a1, bf[n2], acc[1][n2], 0, 0, 0);
        }
    }

    if (z < 2) {
        u16* out = (z == 0) ? Qb : Kb;
#pragma unroll
        for (int m2 = 0; m2 < 2; m2++)
#pragma unroll
            for (int r = 0; r < 4; r++) {
                int lg = mt * 128 + w * 32 + m2 * 16 + g * 4 + r;
                int b_ = lg >> 12, l = lg & 4095;
                u16* op = out + ((size_t)(b_ * HH + h) * LL + l) * DD + c;
#pragma unroll
                for (int n2 = 0; n2 < 8; n2++) op[n2 * 16] = f2bf(acc[m2][n2][r]);
            }
    } else {
        int b_ = mt >> 5;
        int lbase = (mt & 31) * 128;
#pragma unroll
        for (int m2 = 0; m2 < 2; m2++)
#pragma unroll
            for (int r = 0; r < 4; r++) {
                int e = w * 32 + m2 * 16 + g * 4 + r;
                u16* op = Vt + ((size_t)(b_ * HH + h) * DD + e) * LL + lbase + c;
#pragma unroll
                for (int n2 = 0; n2 < 8; n2++) op[n2 * 16] = f2bf(acc[m2][n2][r]);
            }
    }
}

// Flash attention, causal, no-max softmax. Block = 4 waves x 32 q-rows = 128
// q-rows of one head over one 512-key chunk (<=16 steps of 32 keys).
// R8-proven staging: K AND V tiles in LDS (async global_load_lds, 32KB dbuf;
// K XOR-swizzled conflict-free, V 64B rows accepted). 512-key chunks give
// 1152 blocks (4.5/CU dispatched) for residency. Partials: diag chunk ->
// base tile, interior -> private bf16 slots; combined in norm_cast.
__global__ __launch_bounds__(256) void flash_attn(const u16* __restrict__ Q,
                                                  const u16* __restrict__ K,
                                                  const u16* __restrict__ Vt,
                                                  u16* __restrict__ basep,
                                                  u16* __restrict__ slots,
                                                  float* __restrict__ l_acc) {
    __shared__ __align__(16) u16 Kls[2][32 * 128];   // rows k (256B), swizzled
    __shared__ __align__(16) u16 Vls[2][128 * 32];   // rows e (64B)

    int lane = threadIdx.x & 63;
    int w    = threadIdx.x >> 6;          // 0..3
    int c = lane & 15, g = lane >> 4;

    int bid  = blockIdx.x;                // 0..1151
    int head = bid & 7;                   // b*H + h
    int i    = bid >> 3;                  // 0..143
    int t, ch;
    if (i < 120) {                        // full 16-step chunks, longest-lived first
        int rem = i; ch = 0;
        while (rem >= 29 - 4 * ch) { rem -= 29 - 4 * ch; ch++; }
        t = 31 - rem;
    } else {
        int j = i - 120;                  // partial diag chunks, size desc
        if (j < 8)       { t = 30 - 4 * j;        ch = (t - 2) >> 2; }
        else if (j < 16) { t = 29 - 4 * (j - 8);  ch = (t - 1) >> 2; }
        else             { t = 28 - 4 * (j - 16); ch = t >> 2; }
    }

    int kstart = ch << 9;
    int kend   = min((t + 1) << 7, kstart + 512);
    int nsteps = (kend - kstart) >> 5;    // 4..16, block-uniform

    int qb = t * 128 + w * 32;
    int my_steps = min(nsteps, ((qb + 31 - kstart) >> 5) + 1);

    // Q B-fragments for two q-halves (n=c=q-row, k=g*8..)
    short8 bq0[4], bq1[4];
    {
        const u16* qp0 = Q + ((size_t)head * LL + qb + c) * DD + g * 8;
        const u16* qp1 = qp0 + 16 * DD;
#pragma unroll
        for (int kk = 0; kk < 4; kk++) {
            bq0[kk] = *(const short8*)(qp0 + kk * 32);
            bq1[kk] = *(const short8*)(qp1 + kk * 32);
        }
    }

    floatx4 o0[8], o1[8];
#pragma unroll
    for (int tt = 0; tt < 8; tt++) {
        o0[tt] = (floatx4){0.f, 0.f, 0.f, 0.f};
        o1[tt] = (floatx4){0.f, 0.f, 0.f, 0.f};
    }
    float lsum0 = 0.f, lsum1 = 0.f;

    int s0 = c + (((g << 1) & 3) << 4);
    int s1 = c + ((((g << 1) | 1) & 3) << 4);
    bool hi = (g >= 2);

    const u16* Kg0 = K  + ((size_t)head * LL + kstart) * DD;
    const u16* Vg0 = Vt + (size_t)head * DD * LL + kstart;

    int q0 = w * 64 + lane;
    int r0 = q0 >> 4, cc0 = (q0 & 15) ^ (r0 & 15);
    int r1 = r0 + 16,  cc1 = (q0 & 15) ^ (r1 & 15);
    int e0 = q0 >> 2, c40 = (q0 & 3) * 8;
    int e1 = e0 + 64;

#define STAGE(s) {                                                          \
        int buf_ = (s) & 1; int kb_ = (s) << 5;                             \
        const u16* Kg = Kg0 + (size_t)kb_ * DD;                             \
        const u16* Vg = Vg0 + kb_;                                          \
        gld16(Kg + r0 * DD + cc0 * 8, &Kls[buf_][w * 512]);                 \
        gld16(Kg + r1 * DD + cc1 * 8, &Kls[buf_][2048 + w * 512]);          \
        gld16(Vg + (size_t)e0 * LL + c40, &Vls[buf_][w * 512]);             \
        gld16(Vg + (size_t)e1 * LL + c40, &Vls[buf_][2048 + w * 512]);      \
    }

    STAGE(0);

    for (int j = 0; j < nsteps; ++j) {
        __syncthreads();
        if (j + 1 < nsteps) STAGE(j + 1);
        if (j < my_steps) {
            int kb = kstart + (j << 5);
            const u16* Kb_ = &Kls[j & 1][0];
            const u16* Vb_ = &Vls[j & 1][0];

            floatx4 st00 = {0,0,0,0}, st01 = {0,0,0,0};
            floatx4 st10 = {0,0,0,0}, st11 = {0,0,0,0};
            {
                short8 ka[4];
#pragma unroll
                for (int kk = 0; kk < 4; kk++)
                    ka[kk] = *(const short8*)(Kb_ + c * 128 + (((g + 4 * kk) ^ c)) * 8);
#pragma unroll
                for (int kk = 0; kk < 4; kk++) {
                    st00 = __builtin_amdgcn_mfma_f32_16x16x32_bf16(ka[kk], bq0[kk], st00, 0, 0, 0);
                    st10 = __builtin_amdgcn_mfma_f32_16x16x32_bf16(ka[kk], bq1[kk], st10, 0, 0, 0);
                }
#pragma unroll
                for (int kk = 0; kk < 4; kk++)
                    ka[kk] = *(const short8*)(Kb_ + (16 + c) * 128 + (((g + 4 * kk) ^ c)) * 8);
#pragma unroll
                for (int kk = 0; kk < 4; kk++) {
                    st01 = __builtin_amdgcn_mfma_f32_16x16x32_bf16(ka[kk], bq0[kk], st01, 0, 0, 0);
                    st11 = __builtin_amdgcn_mfma_f32_16x16x32_bf16(ka[kk], bq1[kk], st11, 0, 0, 0);
                }
            }

            PFrag au0, au1;
#pragma unroll
            for (int qh = 0; qh < 2; qh++) {
                floatx4 sa = qh ? st10 : st00;
                floatx4 sb = qh ? st11 : st01;
                int qbh = qb + qh * 16;
                float p[8];
                if (kb + 31 > qbh) {
                    int q_c = qbh + c;
#pragma unroll
                    for (int r = 0; r < 4; r++) {
                        int k0 = kb + g * 4 + r;
                        p[r]     = (k0      <= q_c) ? sa[r] : -INFINITY;
                        p[4 + r] = (k0 + 16 <= q_c) ? sb[r] : -INFINITY;
                    }
                } else {
#pragma unroll
                    for (int r = 0; r < 4; r++) { p[r] = sa[r]; p[4 + r] = sb[r]; }
                }
                float ls = 0.f;
#pragma unroll
                for (int i2 = 0; i2 < 8; i2++) { p[i2] = __expf(p[i2]); ls += p[i2]; }
                if (qh) lsum1 += ls; else lsum0 += ls;

                u32 pk00 = pk2bf(p[0], p[1]);
                u32 pk01 = pk2bf(p[2], p[3]);
                u32 pk10 = pk2bf(p[4], p[5]);
                u32 pk11 = pk2bf(p[6], p[7]);
                u32 x00 = (u32)__shfl((int)pk00, s0), x10 = (u32)__shfl((int)pk10, s0);
                u32 x01 = (u32)__shfl((int)pk01, s0), x11 = (u32)__shfl((int)pk11, s0);
                u32 y00 = (u32)__shfl((int)pk00, s1), y10 = (u32)__shfl((int)pk10, s1);
                u32 y01 = (u32)__shfl((int)pk01, s1), y11 = (u32)__shfl((int)pk11, s1);
                PFrag* au = qh ? &au1 : &au0;
                au->u[0] = hi ? x10 : x00;
                au->u[1] = hi ? x11 : x01;
                au->u[2] = hi ? y10 : y00;
                au->u[3] = hi ? y11 : y01;
            }

#pragma unroll
            for (int tt = 0; tt < 8; tt++) {
                short8 vb = *(const short8*)(Vb_ + (tt * 16 + c) * 32 + g * 8);
                o0[tt] = __builtin_amdgcn_mfma_f32_16x16x32_bf16(au0.s, vb, o0[tt], 0, 0, 0);
                o1[tt] = __builtin_amdgcn_mfma_f32_16x16x32_bf16(au1.s, vb, o1[tt], 0, 0, 0);
            }
        }
    }
#undef STAGE

    lsum0 += __shfl_xor(lsum0, 16); lsum0 += __shfl_xor(lsum0, 32);
    lsum1 += __shfl_xor(lsum1, 16); lsum1 += __shfl_xor(lsum1, 32);
    if (g == 0) {
        atomicAdd(&l_acc[head * LL + qb + c],      lsum0);
        atomicAdd(&l_acc[head * LL + qb + 16 + c], lsum1);
    }

    // partial O store as bf16 (one owner per element)
    bool diag = (kstart + 512 >= ((t + 1) << 7));
    u16* dst0 = diag ? basep + ((size_t)head * LL + t * 128) * 128
                     : slots + ((size_t)(head * 112 + pfx2(t) + ch)) * 16384;
    dst0 += (size_t)(w * 32) * 128;
#pragma unroll
    for (int r = 0; r < 4; r++) {
        u16* d0 = dst0 + (g * 4 + r) * 128 + c;
        u16* d1 = d0 + 16 * 128;
#pragma unroll
        for (int tt = 0; tt < 8; tt++) {
            d0[tt * 16] = f2bf(o0[tt][r]);
            d1[tt * 16] = f2bf(o1[tt][r]);
        }
    }
}

// ctx_bf16 = f2bf((base + sum slots) / l)
__global__ __launch_bounds__(256) void norm_cast(const u16* __restrict__ basep,
                                                 const u16* __restrict__ slots,
                                                 const float* __restrict__ l_acc,
                                                 u16* __restrict__ ctx) {
    int i = blockIdx.x * 256 + threadIdx.x;
    int e4 = i * 4;
    int col = e4 & 511;
    int bl  = e4 >> 9;
    int b_ = bl >> 12, l = bl & 4095;
    int h = col >> 7, d = col & 127;
    int head = b_ * HH + h;
    int t = l >> 7;
    int nx = t >> 2;                       // # interior chunks feeding this tile

    ushort4 bv = *(const ushort4*)(basep + ((size_t)head * LL + l) * 128 + d);
    float v0 = bf2f(bv.x), v1 = bf2f(bv.y), v2 = bf2f(bv.z), v3 = bf2f(bv.w);
    if (nx > 0) {
        int sb = head * 112 + pfx2(t);
        for (int x = 0; x < nx; x++) {
            ushort4 sv = *(const ushort4*)(slots + (size_t)(sb + x) * 16384 + (l & 127) * 128 + d);
            v0 += bf2f(sv.x); v1 += bf2f(sv.y); v2 += bf2f(sv.z); v3 += bf2f(sv.w);
        }
    }
    float inv = 1.f / l_acc[head * LL + l];
    ushort4 o;
    o.x = f2bf(v0 * inv); o.y = f2bf(v1 * inv);
    o.z = f2bf(v2 * inv); o.w = f2bf(v3 * inv);
    *(ushort4*)(ctx + e4) = o;
}

// y = ctx(8192x512) @ Wo(128x512)^T -> fp32 [B,L,128]
__global__ __launch_bounds__(256) void proj_out(const u16* __restrict__ ctx,
                                                const u16* __restrict__ wo,
                                                float* __restrict__ y) {
    __shared__ __align__(16) u16 At[2][128 * 64];
    __shared__ __align__(16) u16 Wt[2][128 * 64];
    int lane = threadIdx.x & 63;
    int w    = threadIdx.x >> 6;
    int c = lane & 15, g = lane >> 4;
    int mt = blockIdx.x;                  // 0..63
    const u16* Ag = ctx + (size_t)mt * 128 * 512;

#define PSTAGE(kc) {                                                        \
        int buf_ = (kc) & 1; int ks_ = (kc) * 64;                           \
        _Pragma("unroll")                                                   \
        for (int i = 0; i < 4; i++) {                                       \
            int row = i * 32 + w * 8 + (lane >> 3);                         \
            int cc  = (lane & 7) ^ (row & 7);                               \
            gld16(Ag + (size_t)row * 512 + ks_ + cc * 8,                    \
                  &At[buf_][(i * 32 + w * 8) * 64]);                        \
            gld16(wo + (size_t)row * 512 + ks_ + cc * 8,                    \
                  &Wt[buf_][(i * 32 + w * 8) * 64]);                        \
        }                                                                   \
    }

    floatx4 acc[2][8];
#pragma unroll
    for (int m2 = 0; m2 < 2; m2++)
#pragma unroll
        for (int n2 = 0; n2 < 8; n2++) acc[m2][n2] = (floatx4){0.f, 0.f, 0.f, 0.f};

    PSTAGE(0);
    for (int kc = 0; kc < 8; kc++) {
        __syncthreads();
        if (kc + 1 < 8) PSTAGE(kc + 1);
        int buf = kc & 1;
#pragma unroll
        for (int kk = 0; kk < 2; kk++) {
            int G = g + 4 * kk;
            short8 a0, a1, bf[8];
            {
                int ra = w * 32 + c;
                int rb = ra + 16;
                a0 = *(const short8*)(&At[buf][ra * 64 + ((G ^ (ra & 7)) * 8)]);
                a1 = *(const short8*)(&At[buf][rb * 64 + ((G ^ (rb & 7)) * 8)]);
            }
#pragma unroll
            for (int n2 = 0; n2 < 8; n2++) {
                int rn = n2 * 16 + c;
                bf[n2] = *(const short8*)(&Wt[buf][rn * 64 + ((G ^ (rn & 7)) * 8)]);
            }
#pragma unroll
            for (int n2 = 0; n2 < 8; n2++) {
                acc[0][n2] = __builtin_amdgcn_mfma_f32_16x16x32_bf16(a0, bf[n2], acc[0][n2], 0, 0, 0);
                acc[1][n2] = __builtin_amdgcn_mfma_f32_16x16x32_bf16(a1, bf[n2], acc[1][n2], 0, 0, 0);
            }
        }
    }
#undef PSTAGE

#pragma unroll
    for (int m2 = 0; m2 < 2; m2++)
#pragma unroll
        for (int r = 0; r < 4; r++) {
            int m = mt * 128 + w * 32 + m2 * 16 + g * 4 + r;
            float* yp = y + (size_t)m * 128 + c;
#pragma unroll
            for (int n2 = 0; n2 < 8; n2++) yp[n2 * 16] = acc[m2][n2][r];
        }
}

extern "C" void kernel_launch(void* const* d_in, const int* in_sizes, int n_in,
                              void* d_out, int out_size, void* d_ws, size_t ws_size,
                              hipStream_t stream) {
    const float* x  = (const float*)d_in[0];
    const float* Wq = (const float*)d_in[1];
    const float* Wk = (const float*)d_in[2];
    const float* Wv = (const float*)d_in[3];
    const float* Wo = (const float*)d_in[4];
    float* y = (float*)d_out;

    u16* ws  = (u16*)d_ws;
    u16* xb  = ws;
    u16* wqb = xb  + BB * LL * DD;
    u16* wkb = wqb + HH * DD * DD;
    u16* wvb = wkb + HH * DD * DD;
    u16* wob = wvb + HH * DD * DD;
    u16* Qb  = wob + DD * HH * DD;          // [B,H,L,128]
    u16* Kb  = Qb  + BB * HH * LL * DD;
    u16* Vt  = Kb  + BB * HH * LL * DD;     // [B,H,128,L]
    u16* ctx = Vt  + BB * HH * LL * DD;     // [B,L,512] bf16
    u16* basep = ctx + (size_t)BB * LL * HH * DD;        // [8][L][128] bf16
    u16* slots = basep + (size_t)8 * LL * 128;           // 896 x 16384 bf16
    float* l_acc = (float*)(slots + (size_t)896 * 16384);// [8][L]

    cvt_all<<<dim3(1024, 6), 256, 0, stream>>>(x, Wq, Wk, Wv, Wo,
                                               xb, wqb, wkb, wvb, wob, l_acc);
    proj_qkv<<<dim3(64, 12), 256, 0, stream>>>(xb, wqb, wkb, wvb, Qb, Kb, Vt);
    flash_attn<<<dim3(1152), 256, 0, stream>>>(Qb, Kb, Vt, basep, slots, l_acc);
    norm_cast<<<dim3(4096), 256, 0, stream>>>(basep, slots, l_acc, ctx);
    proj_out<<<dim3(64), 256, 0, stream>>>(ctx, wob, y);
}

// Round 12
// 149.875 us; speedup vs baseline: 1.1892x; 1.1663x over previous
//
#include <hip/hip_runtime.h>
#include <hip/hip_bf16.h>

#define BB 2
#define LL 4096
#define DD 128
#define HH 4

typedef unsigned short u16;
typedef unsigned int u32;
typedef __attribute__((ext_vector_type(8))) short short8;   // 8 bf16
typedef __attribute__((ext_vector_type(4))) float floatx4;

union PFrag { short8 s; u32 u[4]; };

__device__ __forceinline__ u16 f2bf(float f) {
    union { float f; u32 u; } v; v.f = f;
    return (u16)((v.u + 0x7fffu + ((v.u >> 16) & 1u)) >> 16);
}

__device__ __forceinline__ float bf2f(u16 u) {
    union { u32 u; float f; } v; v.u = (u32)u << 16;
    return v.f;
}

// packed f32x2 -> bf16x2 (low = a)
__device__ __forceinline__ u32 pk2bf(float a, float b) {
    union { __hip_bfloat162 h; u32 u; } v;
    v.h = __float22bfloat162_rn(float2{a, b});
    return v.u;
}

// async global->LDS, 16B per lane; lds dest must be wave-uniform base
__device__ __forceinline__ void gld16(const u16* g, u16* l) {
    __builtin_amdgcn_global_load_lds((const __attribute__((address_space(1))) void*)g,
                                     (__attribute__((address_space(3))) void*)l, 16, 0, 0);
}

// # of interior (non-diagonal) 512-key chunks for q-tiles t' < t
__device__ __forceinline__ int pfx2(int t) {
    int a = t >> 2, b = t & 3;
    return 2 * a * (a - 1) + a * b;
}

// z=0: x, z=1..4: weights, z=5: zero l_acc
__global__ __launch_bounds__(256) void cvt_all(const float* __restrict__ x,
                                               const float* __restrict__ wq,
                                               const float* __restrict__ wk,
                                               const float* __restrict__ wv,
                                               const float* __restrict__ wo,
                                               u16* xb, u16* wqb, u16* wkb,
                                               u16* wvb, u16* wob,
                                               float* l_acc) {
    int z = blockIdx.y;
    if (z == 5) {
        int i = (blockIdx.x * 256 + threadIdx.x) * 4;
        if (i < 8 * LL) *(float4*)(l_acc + i) = (float4){0.f, 0.f, 0.f, 0.f};
        return;
    }
    const float* src; u16* dst; int n;
    if      (z == 0) { src = x;  dst = xb;  n = BB * LL * DD; }
    else if (z == 1) { src = wq; dst = wqb; n = HH * DD * DD; }
    else if (z == 2) { src = wk; dst = wkb; n = HH * DD * DD; }
    else if (z == 3) { src = wv; dst = wvb; n = HH * DD * DD; }
    else             { src = wo; dst = wob; n = DD * HH * DD; }
    int i = (blockIdx.x * 256 + threadIdx.x) * 4;
    if (i >= n) return;
    float4 v = *(const float4*)(src + i);
    ushort4 o;
    o.x = f2bf(v.x); o.y = f2bf(v.y); o.z = f2bf(v.z); o.w = f2bf(v.w);
    *(ushort4*)(dst + i) = o;
}

// Tiled QKV projection: 128x128 output tile per block, K=128 one-shot.
__global__ __launch_bounds__(256) void proj_qkv(const u16* __restrict__ xb,
                                                const u16* __restrict__ wqb,
                                                const u16* __restrict__ wkb,
                                                const u16* __restrict__ wvb,
                                                u16* __restrict__ Qb,
                                                u16* __restrict__ Kb,
                                                u16* __restrict__ Vt) {
    __shared__ __align__(16) u16 At[128 * 128];
    __shared__ __align__(16) u16 Wt[128 * 128];
    int lane = threadIdx.x & 63;
    int w    = threadIdx.x >> 6;
    int c = lane & 15, g = lane >> 4;
    int mt = blockIdx.x;                  // 0..63
    int nt = blockIdx.y;                  // 0..11
    int z = nt >> 2, h = nt & 3;
    const u16* Wg = ((z == 0) ? wqb : (z == 1) ? wkb : wvb) + h * 128 * DD;
    const u16* Ag = xb + (size_t)mt * 128 * DD;

#pragma unroll
    for (int i = 0; i < 8; i++) {
        int row = i * 16 + w * 4 + (lane >> 4);
        int cc  = (lane & 15) ^ (row & 15);
        gld16(Ag + row * DD + cc * 8, &At[(i * 16 + w * 4) * 128]);
    }
#pragma unroll
    for (int i = 0; i < 8; i++) {
        int row = i * 16 + w * 4 + (lane >> 4);
        int cc  = (lane & 15) ^ (row & 15);
        gld16(Wg + row * DD + cc * 8, &Wt[(i * 16 + w * 4) * 128]);
    }
    __syncthreads();

    const u16* Abuf = (z < 2) ? At : Wt;   // a-operand rows (m)
    const u16* Bbuf = (z < 2) ? Wt : At;   // b-operand rows (n)

    floatx4 acc[2][8];
#pragma unroll
    for (int m2 = 0; m2 < 2; m2++)
#pragma unroll
        for (int n2 = 0; n2 < 8; n2++) acc[m2][n2] = (floatx4){0.f, 0.f, 0.f, 0.f};

#pragma unroll
    for (int kk = 0; kk < 4; kk++) {
        short8 a0, a1, bf[8];
        {
            int r0 = w * 32 + c;
            int r1 = r0 + 16;
            a0 = *(const short8*)(&Abuf[r0 * 128 + (((g + 4 * kk) ^ (r0 & 15)) * 8)]);
            a1 = *(const short8*)(&Abuf[r1 * 128 + (((g + 4 * kk) ^ (r1 & 15)) * 8)]);
        }
#pragma unroll
        for (int n2 = 0; n2 < 8; n2++) {
            int rn = n2 * 16 + c;
            bf[n2] = *(const short8*)(&Bbuf[rn * 128 + (((g + 4 * kk) ^ (rn & 15)) * 8)]);
        }
#pragma unroll
        for (int n2 = 0; n2 < 8; n2++) {
            acc[0][n2] = __builtin_amdgcn_mfma_f32_16x16x32_bf16(a0, bf[n2], acc[0][n2], 0, 0, 0);
            acc[1][n2] = __builtin_amdgcn_mfma_f32_16x16x32_bf16(a1, bf[n2], acc[1][n2], 0, 0, 0);
        }
    }

    if (z < 2) {
        u16* out = (z == 0) ? Qb : Kb;
#pragma unroll
        for (int m2 = 0; m2 < 2; m2++)
#pragma unroll
            for (int r = 0; r < 4; r++) {
                int lg = mt * 128 + w * 32 + m2 * 16 + g * 4 + r;
                int b_ = lg >> 12, l = lg & 4095;
                u16* op = out + ((size_t)(b_ * HH + h) * LL + l) * DD + c;
#pragma unroll
                for (int n2 = 0; n2 < 8; n2++) op[n2 * 16] = f2bf(acc[m2][n2][r]);
            }
    } else {
        int b_ = mt >> 5;
        int lbase = (mt & 31) * 128;
#pragma unroll
        for (int m2 = 0; m2 < 2; m2++)
#pragma unroll
            for (int r = 0; r < 4; r++) {
                int e = w * 32 + m2 * 16 + g * 4 + r;
                u16* op = Vt + ((size_t)(b_ * HH + h) * DD + e) * LL + lbase + c;
#pragma unroll
                for (int n2 = 0; n2 < 8; n2++) op[n2 * 16] = f2bf(acc[m2][n2][r]);
            }
    }
}

// Flash attention, causal, no-max softmax. Block = 4 waves x 32 q-rows = 128
// q-rows of one head over one 512-key chunk (<=16 steps of 32 keys).
// K+V LDS dbuf staging (R8-proven). __launch_bounds__(256,3): cap total regs
// ~170 (vs ~176 unconstrained incl 64 AGPR acc) -> 3 blocks/CU resident
// instead of 2. R11 showed occupancy pinned at ~17% by register ceiling.
__global__ __launch_bounds__(256, 3) void flash_attn(const u16* __restrict__ Q,
                                                     const u16* __restrict__ K,
                                                     const u16* __restrict__ Vt,
                                                     u16* __restrict__ basep,
                                                     u16* __restrict__ slots,
                                                     float* __restrict__ l_acc) {
    __shared__ __align__(16) u16 Kls[2][32 * 128];   // rows k (256B), swizzled
    __shared__ __align__(16) u16 Vls[2][128 * 32];   // rows e (64B)

    int lane = threadIdx.x & 63;
    int w    = threadIdx.x >> 6;          // 0..3
    int c = lane & 15, g = lane >> 4;

    int bid  = blockIdx.x;                // 0..1151
    int head = bid & 7;                   // b*H + h
    int i    = bid >> 3;                  // 0..143
    int t, ch;
    if (i < 120) {                        // full 16-step chunks, longest-lived first
        int rem = i; ch = 0;
        while (rem >= 29 - 4 * ch) { rem -= 29 - 4 * ch; ch++; }
        t = 31 - rem;
    } else {
        int j = i - 120;                  // partial diag chunks, size desc
        if (j < 8)       { t = 30 - 4 * j;        ch = (t - 2) >> 2; }
        else if (j < 16) { t = 29 - 4 * (j - 8);  ch = (t - 1) >> 2; }
        else             { t = 28 - 4 * (j - 16); ch = t >> 2; }
    }

    int kstart = ch << 9;
    int kend   = min((t + 1) << 7, kstart + 512);
    int nsteps = (kend - kstart) >> 5;    // 4..16, block-uniform

    int qb = t * 128 + w * 32;
    int my_steps = min(nsteps, ((qb + 31 - kstart) >> 5) + 1);

    // Q B-fragments for two q-halves (n=c=q-row, k=g*8..)
    short8 bq0[4], bq1[4];
    {
        const u16* qp0 = Q + ((size_t)head * LL + qb + c) * DD + g * 8;
        const u16* qp1 = qp0 + 16 * DD;
#pragma unroll
        for (int kk = 0; kk < 4; kk++) {
            bq0[kk] = *(const short8*)(qp0 + kk * 32);
            bq1[kk] = *(const short8*)(qp1 + kk * 32);
        }
    }

    floatx4 o0[8], o1[8];
#pragma unroll
    for (int tt = 0; tt < 8; tt++) {
        o0[tt] = (floatx4){0.f, 0.f, 0.f, 0.f};
        o1[tt] = (floatx4){0.f, 0.f, 0.f, 0.f};
    }
    float lsum0 = 0.f, lsum1 = 0.f;

    int s0 = c + (((g << 1) & 3) << 4);
    int s1 = c + ((((g << 1) | 1) & 3) << 4);
    bool hi = (g >= 2);

    const u16* Kg0 = K  + ((size_t)head * LL + kstart) * DD;
    const u16* Vg0 = Vt + (size_t)head * DD * LL + kstart;

    int q0 = w * 64 + lane;
    int r0 = q0 >> 4, cc0 = (q0 & 15) ^ (r0 & 15);
    int r1 = r0 + 16,  cc1 = (q0 & 15) ^ (r1 & 15);
    int e0 = q0 >> 2, c40 = (q0 & 3) * 8;
    int e1 = e0 + 64;

#define STAGE(s) {                                                          \
        int buf_ = (s) & 1; int kb_ = (s) << 5;                             \
        const u16* Kg = Kg0 + (size_t)kb_ * DD;                             \
        const u16* Vg = Vg0 + kb_;                                          \
        gld16(Kg + r0 * DD + cc0 * 8, &Kls[buf_][w * 512]);                 \
        gld16(Kg + r1 * DD + cc1 * 8, &Kls[buf_][2048 + w * 512]);          \
        gld16(Vg + (size_t)e0 * LL + c40, &Vls[buf_][w * 512]);             \
        gld16(Vg + (size_t)e1 * LL + c40, &Vls[buf_][2048 + w * 512]);      \
    }

    STAGE(0);

    for (int j = 0; j < nsteps; ++j) {
        __syncthreads();
        if (j + 1 < nsteps) STAGE(j + 1);
        if (j < my_steps) {
            int kb = kstart + (j << 5);
            const u16* Kb_ = &Kls[j & 1][0];
            const u16* Vb_ = &Vls[j & 1][0];

            floatx4 st00 = {0,0,0,0}, st01 = {0,0,0,0};
            floatx4 st10 = {0,0,0,0}, st11 = {0,0,0,0};
            {
                short8 ka[4];
#pragma unroll
                for (int kk = 0; kk < 4; kk++)
                    ka[kk] = *(const short8*)(Kb_ + c * 128 + (((g + 4 * kk) ^ c)) * 8);
#pragma unroll
                for (int kk = 0; kk < 4; kk++) {
                    st00 = __builtin_amdgcn_mfma_f32_16x16x32_bf16(ka[kk], bq0[kk], st00, 0, 0, 0);
                    st10 = __builtin_amdgcn_mfma_f32_16x16x32_bf16(ka[kk], bq1[kk], st10, 0, 0, 0);
                }
#pragma unroll
                for (int kk = 0; kk < 4; kk++)
                    ka[kk] = *(const short8*)(Kb_ + (16 + c) * 128 + (((g + 4 * kk) ^ c)) * 8);
#pragma unroll
                for (int kk = 0; kk < 4; kk++) {
                    st01 = __builtin_amdgcn_mfma_f32_16x16x32_bf16(ka[kk], bq0[kk], st01, 0, 0, 0);
                    st11 = __builtin_amdgcn_mfma_f32_16x16x32_bf16(ka[kk], bq1[kk], st11, 0, 0, 0);
                }
            }

            PFrag au0, au1;
#pragma unroll
            for (int qh = 0; qh < 2; qh++) {
                floatx4 sa = qh ? st10 : st00;
                floatx4 sb = qh ? st11 : st01;
                int qbh = qb + qh * 16;
                float p[8];
                if (kb + 31 > qbh) {
                    int q_c = qbh + c;
#pragma unroll
                    for (int r = 0; r < 4; r++) {
                        int k0 = kb + g * 4 + r;
                        p[r]     = (k0      <= q_c) ? sa[r] : -INFINITY;
                        p[4 + r] = (k0 + 16 <= q_c) ? sb[r] : -INFINITY;
                    }
                } else {
#pragma unroll
                    for (int r = 0; r < 4; r++) { p[r] = sa[r]; p[4 + r] = sb[r]; }
                }
                float ls = 0.f;
#pragma unroll
                for (int i2 = 0; i2 < 8; i2++) { p[i2] = __expf(p[i2]); ls += p[i2]; }
                if (qh) lsum1 += ls; else lsum0 += ls;

                u32 pk00 = pk2bf(p[0], p[1]);
                u32 pk01 = pk2bf(p[2], p[3]);
                u32 pk10 = pk2bf(p[4], p[5]);
                u32 pk11 = pk2bf(p[6], p[7]);
                u32 x00 = (u32)__shfl((int)pk00, s0), x10 = (u32)__shfl((int)pk10, s0);
                u32 x01 = (u32)__shfl((int)pk01, s0), x11 = (u32)__shfl((int)pk11, s0);
                u32 y00 = (u32)__shfl((int)pk00, s1), y10 = (u32)__shfl((int)pk10, s1);
                u32 y01 = (u32)__shfl((int)pk01, s1), y11 = (u32)__shfl((int)pk11, s1);
                PFrag* au = qh ? &au1 : &au0;
                au->u[0] = hi ? x10 : x00;
                au->u[1] = hi ? x11 : x01;
                au->u[2] = hi ? y10 : y00;
                au->u[3] = hi ? y11 : y01;
            }

#pragma unroll
            for (int tt = 0; tt < 8; tt++) {
                short8 vb = *(const short8*)(Vb_ + (tt * 16 + c) * 32 + g * 8);
                o0[tt] = __builtin_amdgcn_mfma_f32_16x16x32_bf16(au0.s, vb, o0[tt], 0, 0, 0);
                o1[tt] = __builtin_amdgcn_mfma_f32_16x16x32_bf16(au1.s, vb, o1[tt], 0, 0, 0);
            }
        }
    }
#undef STAGE

    lsum0 += __shfl_xor(lsum0, 16); lsum0 += __shfl_xor(lsum0, 32);
    lsum1 += __shfl_xor(lsum1, 16); lsum1 += __shfl_xor(lsum1, 32);
    if (g == 0) {
        atomicAdd(&l_acc[head * LL + qb + c],      lsum0);
        atomicAdd(&l_acc[head * LL + qb + 16 + c], lsum1);
    }

    // partial O store as bf16 (one owner per element)
    bool diag = (kstart + 512 >= ((t + 1) << 7));
    u16* dst0 = diag ? basep + ((size_t)head * LL + t * 128) * 128
                     : slots + ((size_t)(head * 112 + pfx2(t) + ch)) * 16384;
    dst0 += (size_t)(w * 32) * 128;
#pragma unroll
    for (int r = 0; r < 4; r++) {
        u16* d0 = dst0 + (g * 4 + r) * 128 + c;
        u16* d1 = d0 + 16 * 128;
#pragma unroll
        for (int tt = 0; tt < 8; tt++) {
            d0[tt * 16] = f2bf(o0[tt][r]);
            d1[tt * 16] = f2bf(o1[tt][r]);
        }
    }
}

// ctx_bf16 = f2bf((base + sum slots) / l)
__global__ __launch_bounds__(256) void norm_cast(const u16* __restrict__ basep,
                                                 const u16* __restrict__ slots,
                                                 const float* __restrict__ l_acc,
                                                 u16* __restrict__ ctx) {
    int i = blockIdx.x * 256 + threadIdx.x;
    int e4 = i * 4;
    int col = e4 & 511;
    int bl  = e4 >> 9;
    int b_ = bl >> 12, l = bl & 4095;
    int h = col >> 7, d = col & 127;
    int head = b_ * HH + h;
    int t = l >> 7;
    int nx = t >> 2;                       // # interior chunks feeding this tile

    ushort4 bv = *(const ushort4*)(basep + ((size_t)head * LL + l) * 128 + d);
    float v0 = bf2f(bv.x), v1 = bf2f(bv.y), v2 = bf2f(bv.z), v3 = bf2f(bv.w);
    if (nx > 0) {
        int sb = head * 112 + pfx2(t);
        for (int x = 0; x < nx; x++) {
            ushort4 sv = *(const ushort4*)(slots + (size_t)(sb + x) * 16384 + (l & 127) * 128 + d);
            v0 += bf2f(sv.x); v1 += bf2f(sv.y); v2 += bf2f(sv.z); v3 += bf2f(sv.w);
        }
    }
    float inv = 1.f / l_acc[head * LL + l];
    ushort4 o;
    o.x = f2bf(v0 * inv); o.y = f2bf(v1 * inv);
    o.z = f2bf(v2 * inv); o.w = f2bf(v3 * inv);
    *(ushort4*)(ctx + e4) = o;
}

// y = ctx(8192x512) @ Wo(128x512)^T -> fp32 [B,L,128]
__global__ __launch_bounds__(256) void proj_out(const u16* __restrict__ ctx,
                                                const u16* __restrict__ wo,
                                                float* __restrict__ y) {
    __shared__ __align__(16) u16 At[2][128 * 64];
    __shared__ __align__(16) u16 Wt[2][128 * 64];
    int lane = threadIdx.x & 63;
    int w    = threadIdx.x >> 6;
    int c = lane & 15, g = lane >> 4;
    int mt = blockIdx.x;                  // 0..63
    const u16* Ag = ctx + (size_t)mt * 128 * 512;

#define PSTAGE(kc) {                                                        \
        int buf_ = (kc) & 1; int ks_ = (kc) * 64;                           \
        _Pragma("unroll")                                                   \
        for (int i = 0; i < 4; i++) {                                       \
            int row = i * 32 + w * 8 + (lane >> 3);                         \
            int cc  = (lane & 7) ^ (row & 7);                               \
            gld16(Ag + (size_t)row * 512 + ks_ + cc * 8,                    \
                  &At[buf_][(i * 32 + w * 8) * 64]);                        \
            gld16(wo + (size_t)row * 512 + ks_ + cc * 8,                    \
                  &Wt[buf_][(i * 32 + w * 8) * 64]);                        \
        }                                                                   \
    }

    floatx4 acc[2][8];
#pragma unroll
    for (int m2 = 0; m2 < 2; m2++)
#pragma unroll
        for (int n2 = 0; n2 < 8; n2++) acc[m2][n2] = (floatx4){0.f, 0.f, 0.f, 0.f};

    PSTAGE(0);
    for (int kc = 0; kc < 8; kc++) {
        __syncthreads();
        if (kc + 1 < 8) PSTAGE(kc + 1);
        int buf = kc & 1;
#pragma unroll
        for (int kk = 0; kk < 2; kk++) {
            int G = g + 4 * kk;
            short8 a0, a1, bf[8];
            {
                int ra = w * 32 + c;
                int rb = ra + 16;
                a0 = *(const short8*)(&At[buf][ra * 64 + ((G ^ (ra & 7)) * 8)]);
                a1 = *(const short8*)(&At[buf][rb * 64 + ((G ^ (rb & 7)) * 8)]);
            }
#pragma unroll
            for (int n2 = 0; n2 < 8; n2++) {
                int rn = n2 * 16 + c;
                bf[n2] = *(const short8*)(&Wt[buf][rn * 64 + ((G ^ (rn & 7)) * 8)]);
            }
#pragma unroll
            for (int n2 = 0; n2 < 8; n2++) {
                acc[0][n2] = __builtin_amdgcn_mfma_f32_16x16x32_bf16(a0, bf[n2], acc[0][n2], 0, 0, 0);
                acc[1][n2] = __builtin_amdgcn_mfma_f32_16x16x32_bf16(a1, bf[n2], acc[1][n2], 0, 0, 0);
            }
        }
    }
#undef PSTAGE

#pragma unroll
    for (int m2 = 0; m2 < 2; m2++)
#pragma unroll
        for (int r = 0; r < 4; r++) {
            int m = mt * 128 + w * 32 + m2 * 16 + g * 4 + r;
            float* yp = y + (size_t)m * 128 + c;
#pragma unroll
            for (int n2 = 0; n2 < 8; n2++) yp[n2 * 16] = acc[m2][n2][r];
        }
}

extern "C" void kernel_launch(void* const* d_in, const int* in_sizes, int n_in,
                              void* d_out, int out_size, void* d_ws, size_t ws_size,
                              hipStream_t stream) {
    const float* x  = (const float*)d_in[0];
    const float* Wq = (const float*)d_in[1];
    const float* Wk = (const float*)d_in[2];
    const float* Wv = (const float*)d_in[3];
    const float* Wo = (const float*)d_in[4];
    float* y = (float*)d_out;

    u16* ws  = (u16*)d_ws;
    u16* xb  = ws;
    u16* wqb = xb  + BB * LL * DD;
    u16* wkb = wqb + HH * DD * DD;
    u16* wvb = wkb + HH * DD * DD;
    u16* wob = wvb + HH * DD * DD;
    u16* Qb  = wob + DD * HH * DD;          // [B,H,L,128]
    u16* Kb  = Qb  + BB * HH * LL * DD;
    u16* Vt  = Kb  + BB * HH * LL * DD;     // [B,H,128,L]
    u16* ctx = Vt  + BB * HH * LL * DD;     // [B,L,512] bf16
    u16* basep = ctx + (size_t)BB * LL * HH * DD;        // [8][L][128] bf16
    u16* slots = basep + (size_t)8 * LL * 128;           // 896 x 16384 bf16
    float* l_acc = (float*)(slots + (size_t)896 * 16384);// [8][L]

    cvt_all<<<dim3(1024, 6), 256, 0, stream>>>(x, Wq, Wk, Wv, Wo,
                                               xb, wqb, wkb, wvb, wob, l_acc);
    proj_qkv<<<dim3(64, 12), 256, 0, stream>>>(xb, wqb, wkb, wvb, Qb, Kb, Vt);
    flash_attn<<<dim3(1152), 256, 0, stream>>>(Qb, Kb, Vt, basep, slots, l_acc);
    norm_cast<<<dim3(4096), 256, 0, stream>>>(basep, slots, l_acc, ctx);
    proj_out<<<dim3(64), 256, 0, stream>>>(ctx, wob, y);
}